// Round 4
// baseline (278.575 us; speedup 1.0000x reference)
//
#include <hip/hip_runtime.h>
#include <hip/hip_bf16.h>

// Problem: out[128,12288] = [ clip(x[:, :6144] @ R, 0, 1) | zeros ]
// M=128, K=N=6144. R streamed once (151 MB fp32).
// Pipeline: prep (x->bf16 A), trans (R -> bf16 R^T, LDS tile transpose),
// gemm2 (m97-style: global_load_lds staging of R^T rows, MFMA 16x16x32,
// K split 8 ways across XCDs, fp32 partials), reduce (+clip, zero tail).

#define NPIX 12288
#define NV   6144
#define MR   128
#define BNW  32
#define KST  128
#define NSTR (NV / BNW)          // 192 n-stripes
#define PARTF ((size_t)MR * NV)  // floats per partial slot (3MB)

typedef __attribute__((ext_vector_type(8))) short bf16x8;
typedef __attribute__((ext_vector_type(4))) float f32x4;
typedef __attribute__((ext_vector_type(4))) unsigned u32x4;

__device__ __forceinline__ unsigned pk2(float lo, float hi) {
    __hip_bfloat162 h = __float22bfloat162_rn(make_float2(lo, hi));
    union { __hip_bfloat162 h; unsigned u; } v; v.h = h; return v.u;
}

__device__ __forceinline__ void gld16(const void* g, void* l) {
    __builtin_amdgcn_global_load_lds(
        (const __attribute__((address_space(1))) void*)g,
        (__attribute__((address_space(3))) void*)l, 16, 0, 0);
}

// ---- prep: x[:, :6144] fp32 -> bf16 A[128][6144] ----
__global__ __launch_bounds__(256) void prep_kernel(const float* __restrict__ x,
                                                   unsigned short* __restrict__ abf) {
    int q = blockIdx.x * 256 + threadIdx.x;
    int m = q / (NV / 8);
    int r = q % (NV / 8);
    int k = r * 8;
    const float* src = x + (size_t)m * NPIX + k;
    f32x4 a = *(const f32x4*)(src);
    f32x4 b = *(const f32x4*)(src + 4);
    u32x4 o;
    o[0] = pk2(a[0], a[1]); o[1] = pk2(a[2], a[3]);
    o[2] = pk2(b[0], b[1]); o[3] = pk2(b[2], b[3]);
    *(u32x4*)(abf + (size_t)m * NV + k) = o;
}

// ---- trans: R[k][n] fp32 -> RT[n][k] bf16, 64x64 LDS tiles ----
// pitch 65 floats: both phases 2-way-or-free on banks.
__global__ __launch_bounds__(256) void trans_kernel(const float* __restrict__ R,
                                                    unsigned short* __restrict__ RT) {
    __shared__ float T[64][65];
    const int tid = threadIdx.x;
    const int kt = blockIdx.x % (NV / 64);
    const int nt = blockIdx.x / (NV / 64);
    const int k0 = kt * 64, n0 = nt * 64;
    const int colg = (tid & 15) * 4;   // n within tile
    const int rowb = tid >> 4;         // 0..15
    #pragma unroll
    for (int it = 0; it < 4; ++it) {
        const int row = it * 16 + rowb;   // k within tile
        f32x4 v = *(const f32x4*)(R + (size_t)(k0 + row) * NV + n0 + colg);
        #pragma unroll
        for (int j = 0; j < 4; ++j) T[colg + j][row] = v[j];
    }
    __syncthreads();
    const int n = tid >> 2, seg = tid & 3;   // 64 n-rows x 4 segs of 16 k
    float f[16];
    #pragma unroll
    for (int u = 0; u < 16; ++u) f[u] = T[n][seg * 16 + u];
    u32x4 o0, o1;
    o0[0] = pk2(f[0], f[1]);  o0[1] = pk2(f[2], f[3]);
    o0[2] = pk2(f[4], f[5]);  o0[3] = pk2(f[6], f[7]);
    o1[0] = pk2(f[8], f[9]);  o1[1] = pk2(f[10], f[11]);
    o1[2] = pk2(f[12], f[13]); o1[3] = pk2(f[14], f[15]);
    unsigned short* dst = RT + (size_t)(n0 + n) * NV + k0 + seg * 16;
    *(u32x4*)(dst) = o0;
    *(u32x4*)(dst + 8) = o1;
}

// ---- gemm2: A[128][6144]bf16 x RT[n][k]bf16 -> partials ----
// grid 1536 = 192 stripes x 8 k-chunks (chunk = bid&7 -> XCD-aligned).
// Per step: stage B-tile [32 n][128 k] bf16 (8KB) via 2x global_load_lds
// dwordx4 per thread, source pre-swizzled (koff ^ ((n&7)<<4)); ds_read_b128
// with same swizzle; 16 MFMA. Double-buffered, one barrier per step.
__global__ __launch_bounds__(256) void gemm2_kernel(
        const unsigned short* __restrict__ A,
        const unsigned short* __restrict__ RT,
        float* __restrict__ out, float* __restrict__ wpart) {
    __shared__ unsigned char Bs[2][8192];

    const int tid = threadIdx.x;
    const int w = tid >> 6, l = tid & 63;
    const int ln = l & 15, lg = l >> 4;
    const int chunk = blockIdx.x & 7;
    const int nb = blockIdx.x >> 3;
    const int n0 = nb * BNW;
    const int kbase = chunk * 768;     // 6144/8
    const int nsi = 768 / KST;         // 6 steps

    // staging map: two 16B issues per thread cover 8KB
    const int f0 = tid * 16, f1 = 4096 + tid * 16;
    const int n_0 = f0 >> 8, n_1 = f1 >> 8;          // 0..15 / 16..31
    const int ko0 = (f0 & 255) ^ ((n_0 & 7) << 4);
    const int ko1 = (f1 & 255) ^ ((n_1 & 7) << 4);
    const char* g0 = (const char*)(RT + (size_t)(n0 + n_0) * NV + kbase) + ko0;
    const char* g1 = (const char*)(RT + (size_t)(n0 + n_1) * NV + kbase) + ko1;

    size_t arow0 = (size_t)(w * 32 + ln) * NV + kbase + lg * 8;
    size_t arow1 = arow0 + (size_t)16 * NV;

    f32x4 acc[2][2];
    #pragma unroll
    for (int a = 0; a < 2; ++a)
        #pragma unroll
        for (int b = 0; b < 2; ++b) {
            acc[a][b][0] = 0.f; acc[a][b][1] = 0.f;
            acc[a][b][2] = 0.f; acc[a][b][3] = 0.f;
        }

    gld16(g0, &Bs[0][f0]);
    gld16(g1, &Bs[0][f1]);
    __syncthreads();

    const int swn = (ln & 7) << 4;
    #pragma unroll 1
    for (int t = 0; t < nsi; ++t) {
        if (t + 1 < nsi) {
            const int nb2 = (t + 1) & 1;
            gld16(g0 + (t + 1) * 256, &Bs[nb2][f0]);
            gld16(g1 + (t + 1) * 256, &Bs[nb2][f1]);
        }
        const unsigned char* buf = Bs[t & 1];
        bf16x8 afr[2][4];
        #pragma unroll
        for (int ks = 0; ks < 4; ++ks) {
            afr[0][ks] = *(const bf16x8*)(A + arow0 + ks * 32);
            afr[1][ks] = *(const bf16x8*)(A + arow1 + ks * 32);
        }
        #pragma unroll
        for (int nt = 0; nt < 2; ++nt) {
            const int rowb = (nt * 16 + ln) * 256;
            #pragma unroll
            for (int ks = 0; ks < 4; ++ks) {
                bf16x8 bfr = *(const bf16x8*)(buf + rowb + (((lg * 16) + ks * 64) ^ swn));
                acc[0][nt] = __builtin_amdgcn_mfma_f32_16x16x32_bf16(afr[0][ks], bfr, acc[0][nt], 0, 0, 0);
                acc[1][nt] = __builtin_amdgcn_mfma_f32_16x16x32_bf16(afr[1][ks], bfr, acc[1][nt], 0, 0, 0);
            }
        }
        arow0 += KST; arow1 += KST;
        __syncthreads();
    }

    float* dst;
    size_t rstride;
    if (chunk < 2) { dst = out + (size_t)chunk * NV; rstride = NPIX; }
    else           { dst = wpart + (size_t)(chunk - 2) * PARTF; rstride = NV; }
    #pragma unroll
    for (int mt = 0; mt < 2; ++mt) {
        const int mbase = w * 32 + mt * 16 + lg * 4;
        #pragma unroll
        for (int nt = 0; nt < 2; ++nt) {
            const size_t cb = (size_t)(n0 + nt * 16 + ln);
            #pragma unroll
            for (int j = 0; j < 4; ++j)
                dst[(size_t)(mbase + j) * rstride + cb] = acc[mt][nt][j];
        }
    }
}

// ---- fallback gemm (proven R1 path), used only if ws too small ----
__device__ __forceinline__ bf16x8 cvt8(f32x4 a, f32x4 b) {
    union { unsigned u[4]; bf16x8 v; } r;
    r.u[0] = pk2(a[0], a[1]); r.u[1] = pk2(a[2], a[3]);
    r.u[2] = pk2(b[0], b[1]); r.u[3] = pk2(b[2], b[3]);
    return r.v;
}

__device__ __forceinline__ void sload(const float*& bptr, float2 (&r)[8]) {
    #pragma unroll
    for (int gi = 0; gi < 4; ++gi) {
        const float* p = bptr + (size_t)(gi * 32) * NV;
        r[2 * gi]     = *(const float2*)(p);
        r[2 * gi + 1] = *(const float2*)(p + NV);
    }
    bptr += (size_t)KST * NV;
}

__device__ __forceinline__ void wstage(unsigned char* buf, const float2 (&r)[8],
                                       int kq, int nq, int sw0, int sw1) {
    #pragma unroll
    for (int gi = 0; gi < 4; ++gi) {
        unsigned lo = pk2(r[2 * gi].x, r[2 * gi + 1].x);
        unsigned hi = pk2(r[2 * gi].y, r[2 * gi + 1].y);
        const int kbyte = (kq + gi * 32) * 2;
        *(unsigned*)(buf + nq * 256       + (kbyte ^ sw0)) = lo;
        *(unsigned*)(buf + (nq + 1) * 256 + (kbyte ^ sw1)) = hi;
    }
}

__device__ __forceinline__ void compute_fb(const unsigned char* buf,
        const float* __restrict__ X, size_t arow0, size_t arow1,
        int ln, int lg, f32x4 (&acc)[2][2]) {
    bf16x8 afr[2][4];
    #pragma unroll
    for (int ks = 0; ks < 4; ++ks) {
        f32x4 p0 = *(const f32x4*)(X + arow0 + ks * 32);
        f32x4 p1 = *(const f32x4*)(X + arow0 + ks * 32 + 4);
        afr[0][ks] = cvt8(p0, p1);
        f32x4 q0 = *(const f32x4*)(X + arow1 + ks * 32);
        f32x4 q1 = *(const f32x4*)(X + arow1 + ks * 32 + 4);
        afr[1][ks] = cvt8(q0, q1);
    }
    const int swn = (ln & 7) << 4;
    #pragma unroll
    for (int nt = 0; nt < 2; ++nt) {
        const int rowb = (nt * 16 + ln) * 256;
        #pragma unroll
        for (int ks = 0; ks < 4; ++ks) {
            bf16x8 bfr = *(const bf16x8*)(buf + rowb + (((lg * 16) + ks * 64) ^ swn));
            acc[0][nt] = __builtin_amdgcn_mfma_f32_16x16x32_bf16(afr[0][ks], bfr, acc[0][nt], 0, 0, 0);
            acc[1][nt] = __builtin_amdgcn_mfma_f32_16x16x32_bf16(afr[1][ks], bfr, acc[1][nt], 0, 0, 0);
        }
    }
}

__global__ __launch_bounds__(256) void gemm_fb_kernel(const float* __restrict__ X,
        const float* __restrict__ R, float* __restrict__ out) {
    __shared__ unsigned char Bs0[32 * 256];
    __shared__ unsigned char Bs1[32 * 256];
    const int tid = threadIdx.x;
    const int w = tid >> 6, l = tid & 63;
    const int ln = l & 15, lg = l >> 4;
    const int chunk = blockIdx.x / NSTR;
    const int nb = blockIdx.x % NSTR;
    const int n0 = nb * BNW;
    const int kbase = chunk * (NV / 2);
    const int nsi = (NV / 2) / KST;
    const int kq = (tid >> 4) * 2;
    const int nq = (tid & 15) * 2;
    const float* bptr = R + (size_t)(kbase + kq) * NV + (n0 + nq);
    const int sw0 = (nq & 7) << 4;
    const int sw1 = ((nq + 1) & 7) << 4;
    size_t arow0 = (size_t)(w * 32 + ln) * NPIX + kbase + lg * 8;
    size_t arow1 = arow0 + (size_t)16 * NPIX;
    f32x4 acc[2][2];
    #pragma unroll
    for (int a = 0; a < 2; ++a)
        #pragma unroll
        for (int b = 0; b < 2; ++b) {
            acc[a][b][0] = 0.f; acc[a][b][1] = 0.f;
            acc[a][b][2] = 0.f; acc[a][b][3] = 0.f;
        }
    float2 ring0[8], ring1[8];
    sload(bptr, ring0);
    sload(bptr, ring1);
    wstage(Bs0, ring0, kq, nq, sw0, sw1);
    __syncthreads();
    #pragma unroll 1
    for (int it = 0; it < nsi / 2; ++it) {
        const int s = it * 2;
        if (s + 2 < nsi) sload(bptr, ring0);
        compute_fb(Bs0, X, arow0, arow1, ln, lg, acc);
        arow0 += KST; arow1 += KST;
        wstage(Bs1, ring1, kq, nq, sw0, sw1);
        __syncthreads();
        if (s + 3 < nsi) sload(bptr, ring1);
        compute_fb(Bs1, X, arow0, arow1, ln, lg, acc);
        arow0 += KST; arow1 += KST;
        if (s + 2 < nsi) wstage(Bs0, ring0, kq, nq, sw0, sw1);
        __syncthreads();
    }
    float* dst = out + (size_t)chunk * NV;
    #pragma unroll
    for (int mt = 0; mt < 2; ++mt) {
        const int mbase = w * 32 + mt * 16 + lg * 4;
        #pragma unroll
        for (int nt = 0; nt < 2; ++nt) {
            const size_t cb = (size_t)(n0 + nt * 16 + ln);
            #pragma unroll
            for (int j = 0; j < 4; ++j)
                dst[(size_t)(mbase + j) * NPIX + cb] = acc[mt][nt][j];
        }
    }
}

// ---- reduce: out[:, :6144] = clip(sum of partials), out[:, 6144:] = 0 ----
__global__ __launch_bounds__(256) void reduce_kernel(float* __restrict__ out,
        const float* __restrict__ wpart, int nextra) {
    int q = blockIdx.x * 256 + threadIdx.x;
    int m = q / (NV / 4);
    int r = q % (NV / 4);
    size_t base = (size_t)m * NPIX + r * 4;
    f32x4 a = *(f32x4*)(out + base);
    f32x4 b = *(f32x4*)(out + base + NV);
    #pragma unroll
    for (int i = 0; i < 4; ++i) a[i] += b[i];
    #pragma unroll 1
    for (int p = 0; p < nextra; ++p) {
        f32x4 c = *(const f32x4*)(wpart + (size_t)p * PARTF + (size_t)m * NV + r * 4);
        #pragma unroll
        for (int i = 0; i < 4; ++i) a[i] += c[i];
    }
    f32x4 cz, z;
    #pragma unroll
    for (int i = 0; i < 4; ++i) {
        cz[i] = fminf(fmaxf(a[i], 0.f), 1.f);
        z[i] = 0.f;
    }
    *(f32x4*)(out + base) = cz;
    *(f32x4*)(out + base + NV) = z;
}

extern "C" void kernel_launch(void* const* d_in, const int* in_sizes, int n_in,
                              void* d_out, int out_size, void* d_ws, size_t ws_size,
                              hipStream_t stream) {
    const float* x = (const float*)d_in[0];
    const float* R = (const float*)d_in[1];
    float* out = (float*)d_out;

    const size_t abytes  = (size_t)MR * NV * 2;        // 1.5 MB
    const size_t rtbytes = (size_t)NV * NV * 2;        // 75.5 MB
    const size_t pbytes  = 6 * PARTF * 4;              // 18 MB

    if (ws_size >= abytes + rtbytes + pbytes) {
        unsigned short* abf = (unsigned short*)d_ws;
        unsigned short* rt  = (unsigned short*)((char*)d_ws + abytes);
        float* wpart = (float*)((char*)d_ws + abytes + rtbytes);
        prep_kernel<<<(MR * NV / 8) / 256, 256, 0, stream>>>(x, abf);
        trans_kernel<<<(NV / 64) * (NV / 64), 256, 0, stream>>>(R, rt);
        gemm2_kernel<<<NSTR * 8, 256, 0, stream>>>(abf, rt, out, wpart);
        reduce_kernel<<<(MR * NV / 4) / 256, 256, 0, stream>>>(out, wpart, 6);
    } else {
        gemm_fb_kernel<<<NSTR * 2, 256, 0, stream>>>(x, R, out);
        reduce_kernel<<<(MR * NV / 4) / 256, 256, 0, stream>>>(out, nullptr, 0);
    }
}